// Round 9
// baseline (284.272 us; speedup 1.0000x reference)
//
#include <hip/hip_runtime.h>
#include <cstdint>
#include <cstddef>

#define Bn 64
#define Tn 2048
#define Un 512
#define QSn 512
#define MSn 512
#define NCHK 16

using f32x16 = __attribute__((ext_vector_type(16))) float;
using bf16x8 = __attribute__((ext_vector_type(8))) short;

__device__ __forceinline__ unsigned short f2bf(float x) {
    unsigned int u = __float_as_uint(x);
    u += 0x7FFFu + ((u >> 16) & 1u);
    return (unsigned short)(u >> 16);
}

__device__ __forceinline__ unsigned int pk2bf(float lo, float hi) {
    unsigned int r;
    asm("v_cvt_pk_bf16_f32 %0, %1, %2" : "=v"(r) : "v"(lo), "v"(hi));
    return r;
}

__device__ __forceinline__ bf16x8 cvt8(float4 a, float4 b) {
    union { unsigned int u[4]; bf16x8 v; } r;
    r.u[0] = pk2bf(a.x, a.y);
    r.u[1] = pk2bf(a.z, a.w);
    r.u[2] = pk2bf(b.x, b.y);
    r.u[3] = pk2bf(b.z, b.w);
    return r.v;
}

__device__ __forceinline__ float tanh_fast(float x) {
    float e = exp2f(x * 2.885390043258667f);   // e^{2x}
    return 1.f - 2.f * __builtin_amdgcn_rcpf(e + 1.f);
}

// async global->LDS, 16B per lane; LDS dest = wave-uniform base + lane*16
#define GLOAD(G, L) __builtin_amdgcn_global_load_lds( \
    (const __attribute__((address_space(1))) void*)(G), \
    (__attribute__((address_space(3))) void*)(L), 16, 0, 0)

// ---------------- Wm f32 -> bf16 pre-convert ----------------
__global__ __launch_bounds__(256) void cvt_kernel(const float* __restrict__ src,
                                                  unsigned short* __restrict__ dst) {
    int i = blockIdx.x * 256 + threadIdx.x;  // one float4 per thread
    float4 v = *(const float4*)(src + (size_t)i * 4);
    ushort4 h = { f2bf(v.x), f2bf(v.y), f2bf(v.z), f2bf(v.w) };
    *(ushort4*)&dst[(size_t)i * 4] = h;
}

// ---------------- pq = query @ Wq^T : [B,U] ----------------
__global__ __launch_bounds__(128) void pq_kernel(const float* __restrict__ query,
                                                 const float* __restrict__ Wq,
                                                 float* __restrict__ pq) {
    __shared__ float ql[QSn];
    const int b = blockIdx.x;
    const int quad = blockIdx.y;
    const int tid = threadIdx.x;
    for (int i = tid; i < QSn; i += 128) ql[i] = query[(size_t)b * QSn + i];
    __syncthreads();
    const int u = quad * 128 + tid;
    const float* w = Wq + (size_t)u * QSn;
    float a0 = 0.f, a1 = 0.f;
    #pragma unroll 4
    for (int k = 0; k < QSn; k += 8) {
        float4 w0 = *(const float4*)(w + k);
        float4 w1 = *(const float4*)(w + k + 4);
        float4 q0 = *(const float4*)(ql + k);
        float4 q1 = *(const float4*)(ql + k + 4);
        a0 += w0.x * q0.x + w0.y * q0.y + w0.z * q0.z + w0.w * q0.w;
        a1 += w1.x * q1.x + w1.y * q1.y + w1.z * q1.z + w1.w * q1.w;
    }
    pq[(size_t)b * Un + u] = a0 + a1;
}

// ---------------- fused score+softmax+context (v9) ----------------
// One block per (b, 128-t chunk). 256 thr = 4 waves (2m x 2n), wave tile 64x64.
// uh-loop 0..3 over 128-u blocks reuses the 2x2 acc:
//   A (keys f32) reg-staged -> cvt_pk -> LDS bf16 (16 KB, XOR-swz granules);
//   B (Wm bf16) GLOAD'd into a DOUBLE-buffered 2x16 KB LDS (latency hidden
//   under MFMA via raw lgkm-only barrier2); score accumulated in LDS stot.
// Then: chunk softmax partials (m, l) + exp weights; context partial
// ctx_c = sum_t exp(s_t - m) * keys[t][:] with keys re-read from L2.
// A merge kernel combines the 16 chunks per batch flash-style.
__global__ __launch_bounds__(256, 3) void fused_kernel(const float* __restrict__ keys,
                                                       const unsigned short* __restrict__ WmB,
                                                       const float* __restrict__ pq,
                                                       const float* __restrict__ Wa,
                                                       float* __restrict__ score_out,
                                                       float* __restrict__ pm,
                                                       float* __restrict__ pl,
                                                       float* __restrict__ pctx) {
    __shared__ __align__(16) unsigned short Ah[128 * 64];     // 16 KB
    __shared__ __align__(16) unsigned short Bh[2][128 * 64];  // 32 KB
    __shared__ float sc_lds[2][128];
    __shared__ float stot[128];
    __shared__ float wexp[128];
    __shared__ float red[4];

    const int tid = threadIdx.x;
    const int lane = tid & 63;
    const int w = tid >> 6;
    const int wm = w >> 1;
    const int wn = w & 1;
    const int lc = lane & 31;
    const int l5 = lane >> 5;
    const int b = blockIdx.y;
    const int chunk = blockIdx.x;
    const int t0 = chunk * 128;

    // A staging: thread owns row ar = tid>>1, 32 f32 cols at ac = (tid&1)*32.
    const int ar = tid >> 1;
    const int ac = (tid & 1) * 32;
    const float* gA = keys + ((size_t)b * Tn + t0 + ar) * MSn + ac;
    int woffA[4];
    #pragma unroll
    for (int j = 0; j < 4; ++j)
        woffA[j] = ar * 64 + ((((tid & 1) * 4 + j) ^ (ar & 7)) * 8);

    // B staging via GLOAD (R8 geometry): wave w rows w*32..+32, 4x1KB.
    const int srow = lane >> 3;
    const int sco = (((lane & 7) ^ srow) << 3);
    char* bDst[2] = { (char*)&Bh[0][0] + w * 4096, (char*)&Bh[1][0] + w * 4096 };

    if (tid < 128) stot[tid] = 0.f;

    #pragma unroll 1
    for (int uh = 0; uh < 4; ++uh) {
        const int u0 = uh * 128;
        const unsigned short* gB = WmB + ((size_t)(u0 + w * 32 + srow)) * MSn + sco;

        f32x16 acc[2][2];
        #pragma unroll
        for (int mf = 0; mf < 2; ++mf)
            #pragma unroll
            for (int nf = 0; nf < 2; ++nf)
                #pragma unroll
                for (int r = 0; r < 16; ++r) acc[mf][nf][r] = 0.f;

        // prologue: A(0) regs -> cvt -> Ah; GLOAD B(0) -> Bh[0]
        {
            float4 a[8];
            #pragma unroll
            for (int j = 0; j < 8; ++j) a[j] = *(const float4*)(gA + j * 4);
            __builtin_amdgcn_sched_barrier(0);
            #pragma unroll
            for (int i = 0; i < 4; ++i) GLOAD(gB + (size_t)i * 8 * MSn, bDst[0] + i * 1024);
            __builtin_amdgcn_sched_barrier(0);
            #pragma unroll
            for (int i = 0; i < 4; ++i)
                *(bf16x8*)&Ah[woffA[i]] = cvt8(a[2 * i], a[2 * i + 1]);
        }

        #pragma unroll
        for (int kt = 0; kt < 8; ++kt) {
            __syncthreads();   // barrier1: Ah(kt) + Bh[kt&1] visible (full drain)

            float4 a[8];
            if (kt < 7) {
                // A(kt+1) loads first (older in FIFO -> cvt waits vmcnt(4))
                #pragma unroll
                for (int j = 0; j < 8; ++j) a[j] = *(const float4*)(gA + (kt + 1) * 64 + j * 4);
                __builtin_amdgcn_sched_barrier(0);
                // B(kt+1) GLOAD into other buffer; stays in flight across barrier2
                #pragma unroll
                for (int i = 0; i < 4; ++i)
                    GLOAD(gB + (kt + 1) * 64 + (size_t)i * 8 * MSn, bDst[(kt + 1) & 1] + i * 1024);
                __builtin_amdgcn_sched_barrier(0);
            }

            // MFMA on A(kt), B(kt)
            const unsigned short* bb = &Bh[kt & 1][0];
            #pragma unroll
            for (int ks = 0; ks < 4; ++ks) {
                bf16x8 af[2], bfr[2];
                #pragma unroll
                for (int mf = 0; mf < 2; ++mf) {
                    int r = wm * 64 + mf * 32 + lc;
                    int g = (ks * 2 + l5) ^ (r & 7);
                    af[mf] = *(const bf16x8*)&Ah[r * 64 + g * 8];
                }
                #pragma unroll
                for (int nf = 0; nf < 2; ++nf) {
                    int ru = wn * 64 + nf * 32 + lc;
                    int bg = (ks * 2 + l5) ^ (ru & 7);
                    bfr[nf] = *(const bf16x8*)&bb[ru * 64 + bg * 8];
                }
                #pragma unroll
                for (int mf = 0; mf < 2; ++mf)
                    #pragma unroll
                    for (int nf = 0; nf < 2; ++nf)
                        acc[mf][nf] = __builtin_amdgcn_mfma_f32_32x32x16_bf16(
                            af[mf], bfr[nf], acc[mf][nf], 0, 0, 0);
            }

            // barrier2: lgkm-only (ds_reads done; vmcnt loads stay in flight)
            asm volatile("s_waitcnt lgkmcnt(0)" ::: "memory");
            __builtin_amdgcn_s_barrier();
            __builtin_amdgcn_sched_barrier(0);

            // stage A(kt+1): cvt (compiler waits A loads, counted) + ds_write
            if (kt < 7) {
                #pragma unroll
                for (int i = 0; i < 4; ++i)
                    *(bf16x8*)&Ah[woffA[i]] = cvt8(a[2 * i], a[2 * i + 1]);
            }
        }

        // uh epilogue: tanh + Wa reduce into stot
        // C layout: col(u)=lc, row(t)=mf*32+(r&3)+8*(r>>2)+4*l5
        float pqv[2], wav[2];
        #pragma unroll
        for (int nf = 0; nf < 2; ++nf) {
            int u = u0 + wn * 64 + nf * 32 + lc;
            pqv[nf] = pq[(size_t)b * Un + u];
            wav[nf] = Wa[u];
        }
        #pragma unroll
        for (int mf = 0; mf < 2; ++mf) {
            #pragma unroll
            for (int r = 0; r < 16; ++r) {
                float s = tanh_fast(acc[mf][0][r] + pqv[0]) * wav[0]
                        + tanh_fast(acc[mf][1][r] + pqv[1]) * wav[1];
                s += __shfl_xor(s, 16);
                s += __shfl_xor(s, 8);
                s += __shfl_xor(s, 4);
                s += __shfl_xor(s, 2);
                s += __shfl_xor(s, 1);
                if (lc == 0)
                    sc_lds[wn][wm * 64 + mf * 32 + (r & 3) + 8 * (r >> 2) + 4 * l5] = s;
            }
        }
        __syncthreads();
        if (tid < 128) stot[tid] += sc_lds[0][tid] + sc_lds[1][tid];
        __syncthreads();
    }

    // ---- write raw scores
    float v = -1e30f;
    if (tid < 128) {
        v = stot[tid];
        score_out[(size_t)b * Tn + t0 + tid] = v;
    }

    // ---- chunk softmax partials: m = max, l = sum exp(v-m)
    float mx = v;
    #pragma unroll
    for (int off = 32; off; off >>= 1) mx = fmaxf(mx, __shfl_xor(mx, off));
    if (lane == 0) red[w] = mx;
    __syncthreads();
    const float m = fmaxf(fmaxf(red[0], red[1]), fmaxf(red[2], red[3]));
    float e = (tid < 128) ? __expf(v - m) : 0.f;
    if (tid < 128) wexp[tid] = e;
    float sum = e;
    #pragma unroll
    for (int off = 32; off; off >>= 1) sum += __shfl_xor(sum, off);
    __syncthreads();           // everyone has read red for m
    if (lane == 0) red[w] = sum;
    __syncthreads();
    const float l = (red[0] + red[1]) + (red[2] + red[3]);

    // ---- context partial: thread owns 2 m-cols; keys rows re-read from L2
    const int c0 = tid * 2;
    const float* kp = keys + ((size_t)b * Tn + t0) * MSn + c0;
    float cx = 0.f, cy = 0.f;
    #pragma unroll 4
    for (int t = 0; t < 128; ++t) {
        float2 kv = *(const float2*)(kp + (size_t)t * MSn);
        float wt = wexp[t];
        cx += wt * kv.x;
        cy += wt * kv.y;
    }
    float2 cacc = { cx, cy };
    *(float2*)&pctx[((size_t)(b * NCHK + chunk)) * MSn + c0] = cacc;
    if (tid == 0) {
        pm[b * NCHK + chunk] = m;
        pl[b * NCHK + chunk] = l;
    }
}

// ---------------- merge chunk partials -> total_context ----------------
__global__ __launch_bounds__(512) void merge_kernel(const float* __restrict__ pm,
                                                    const float* __restrict__ pl,
                                                    const float* __restrict__ pctx,
                                                    float* __restrict__ ctx) {
    __shared__ float sm[NCHK], sl[NCHK];
    const int b = blockIdx.x, tid = threadIdx.x;
    if (tid < NCHK) {
        sm[tid] = pm[b * NCHK + tid];
        sl[tid] = pl[b * NCHK + tid];
    }
    __syncthreads();
    float M = -1e30f;
    #pragma unroll
    for (int c = 0; c < NCHK; ++c) M = fmaxf(M, sm[c]);
    float L = 0.f;
    #pragma unroll
    for (int c = 0; c < NCHK; ++c) L += sl[c] * __expf(sm[c] - M);
    const float inv = 1.f / L;
    float acc = 0.f;
    #pragma unroll
    for (int c = 0; c < NCHK; ++c)
        acc += __expf(sm[c] - M) * pctx[((size_t)(b * NCHK + c)) * MSn + tid];
    ctx[(size_t)b * MSn + tid] = acc * inv;
}

extern "C" void kernel_launch(void* const* d_in, const int* in_sizes, int n_in,
                              void* d_out, int out_size, void* d_ws, size_t ws_size,
                              hipStream_t stream) {
    const float* query = (const float*)d_in[0];
    const float* keys  = (const float*)d_in[1];
    const float* Wq    = (const float*)d_in[2];
    const float* Wm    = (const float*)d_in[3];
    const float* Wa    = (const float*)d_in[4];

    float* ctx_out   = (float*)d_out;                    // [64][512]
    float* score_out = (float*)d_out + (size_t)Bn * MSn; // [64][2048]

    char* ws = (char*)d_ws;
    float* ws_pq   = (float*)(ws);                       // 128 KB
    unsigned short* ws_wmbf = (unsigned short*)(ws + 131072);  // 512 KB
    float* ws_pm   = (float*)(ws + 655360);              // 4 KB
    float* ws_pl   = (float*)(ws + 659456);              // 4 KB
    float* ws_pctx = (float*)(ws + 663552);              // 2 MB  [64][16][512]

    cvt_kernel<<<(Un * MSn / 4) / 256, 256, 0, stream>>>(Wm, ws_wmbf);
    pq_kernel<<<dim3(Bn, 4), 128, 0, stream>>>(query, Wq, ws_pq);
    fused_kernel<<<dim3(NCHK, Bn), 256, 0, stream>>>(keys, ws_wmbf, ws_pq, Wa,
                                                     score_out, ws_pm, ws_pl, ws_pctx);
    merge_kernel<<<Bn, 512, 0, stream>>>(ws_pm, ws_pl, ws_pctx, ctx_out);
}

// Round 10
// 179.451 us; speedup vs baseline: 1.5841x; 1.5841x over previous
//
#include <hip/hip_runtime.h>
#include <cstdint>
#include <cstddef>

#define Bn 64
#define Tn 2048
#define Un 512
#define QSn 512
#define MSn 512
#define TCH 64
#define NCH 32   // chunks per batch = Tn/TCH

using f32x16 = __attribute__((ext_vector_type(16))) float;
using bf16x8 = __attribute__((ext_vector_type(8))) short;

__device__ __forceinline__ unsigned short f2bf(float x) {
    unsigned int u = __float_as_uint(x);
    u += 0x7FFFu + ((u >> 16) & 1u);
    return (unsigned short)(u >> 16);
}

__device__ __forceinline__ unsigned int pk2bf(float lo, float hi) {
    unsigned int r;
    asm("v_cvt_pk_bf16_f32 %0, %1, %2" : "=v"(r) : "v"(lo), "v"(hi));
    return r;
}

__device__ __forceinline__ bf16x8 cvt8(float4 a, float4 b) {
    union { unsigned int u[4]; bf16x8 v; } r;
    r.u[0] = pk2bf(a.x, a.y);
    r.u[1] = pk2bf(a.z, a.w);
    r.u[2] = pk2bf(b.x, b.y);
    r.u[3] = pk2bf(b.z, b.w);
    return r.v;
}

__device__ __forceinline__ float tanh_fast(float x) {
    float e = exp2f(x * 2.885390043258667f);   // e^{2x}
    return 1.f - 2.f * __builtin_amdgcn_rcpf(e + 1.f);
}

// async global->LDS, 16B per lane; LDS dest = wave-uniform base + lane*16
#define GLOAD(G, L) __builtin_amdgcn_global_load_lds( \
    (const __attribute__((address_space(1))) void*)(G), \
    (__attribute__((address_space(3))) void*)(L), 16, 0, 0)

// counted-vmcnt phase barrier (each wave waits its OWN staging, then syncs)
#define PIPE_BAR(N) do { \
    asm volatile("s_waitcnt vmcnt(" #N ") lgkmcnt(0)" ::: "memory"); \
    __builtin_amdgcn_s_barrier(); \
    __builtin_amdgcn_sched_barrier(0); } while (0)

// ---------------- Wm f32 -> bf16 pre-convert ----------------
__global__ __launch_bounds__(256) void cvt_kernel(const float* __restrict__ src,
                                                  unsigned short* __restrict__ dst) {
    int i = blockIdx.x * 256 + threadIdx.x;  // one float4 per thread
    float4 v = *(const float4*)(src + (size_t)i * 4);
    ushort4 h = { f2bf(v.x), f2bf(v.y), f2bf(v.z), f2bf(v.w) };
    *(ushort4*)&dst[(size_t)i * 4] = h;
}

// ---------------- pq = query @ Wq^T : [B,U] ----------------
__global__ __launch_bounds__(128) void pq_kernel(const float* __restrict__ query,
                                                 const float* __restrict__ Wq,
                                                 float* __restrict__ pq) {
    __shared__ float ql[QSn];
    const int b = blockIdx.x;
    const int quad = blockIdx.y;
    const int tid = threadIdx.x;
    for (int i = tid; i < QSn; i += 128) ql[i] = query[(size_t)b * QSn + i];
    __syncthreads();
    const int u = quad * 128 + tid;
    const float* w = Wq + (size_t)u * QSn;
    float a0 = 0.f, a1 = 0.f;
    #pragma unroll 4
    for (int k = 0; k < QSn; k += 8) {
        float4 w0 = *(const float4*)(w + k);
        float4 w1 = *(const float4*)(w + k + 4);
        float4 q0 = *(const float4*)(ql + k);
        float4 q1 = *(const float4*)(ql + k + 4);
        a0 += w0.x * q0.x + w0.y * q0.y + w0.z * q0.z + w0.w * q0.w;
        a1 += w1.x * q1.x + w1.y * q1.y + w1.z * q1.z + w1.w * q1.w;
    }
    pq[(size_t)b * Un + u] = a0 + a1;
}

// ---------------- fused score+softmax+context (v10: uh-inner) ----------------
// Block = (b, 64-t chunk), 256 thr = 4 waves (wm=w>>1 m-half, wn=w&1 u-half).
// Keys chunk staged ONCE per kt (f32 regs -> cvt_pk -> bf16 LDS dbuf 2x8KB).
// Per kt: 4 phases, phase uh: GLOAD next B tile (128u x 64k, ring-2 16KB) ->
// counted vmcnt + raw barrier -> 8 MFMA into acc[uh][nf] (128 VGPR = full U).
// Epilogue: tanh+Wa reduce -> chunk softmax partials (m,l) -> ctx partial from
// keys re-read (L2/L3-hot). Merge kernel combines the 32 chunks flash-style.
__global__ __launch_bounds__(256, 2) void fused_kernel(const float* __restrict__ keys,
                                                       const unsigned short* __restrict__ WmB,
                                                       const float* __restrict__ pq,
                                                       const float* __restrict__ Wa,
                                                       float* __restrict__ score_out,
                                                       float* __restrict__ pm,
                                                       float* __restrict__ pl,
                                                       float* __restrict__ pctx) {
    __shared__ __align__(16) unsigned short Ah[2][TCH * 64];   // 2 x 8 KB
    __shared__ __align__(16) unsigned short Bh[2][128 * 64];   // 2 x 16 KB
    __shared__ float sc_lds[2][TCH];
    __shared__ float stot[TCH];
    __shared__ float wexp[TCH];

    const int tid = threadIdx.x;
    const int lane = tid & 63;
    const int w = tid >> 6;
    const int wm = w >> 1;
    const int wn = w & 1;
    const int lc = lane & 31;
    const int l5 = lane >> 5;
    const int b = blockIdx.y;
    const int chunk = blockIdx.x;
    const int t0 = chunk * TCH;

    // ---- A staging: thread owns row ar, source granules g0,g0+1 (8 f32 each)
    const int ar = tid >> 2;
    const int g0 = (tid & 3) * 2;
    const float* gA = keys + ((size_t)b * Tn + t0 + ar) * MSn + g0 * 8;
    const int wofA0 = ar * 64 + ((g0 ^ (ar & 7)) * 8);
    const int wofA1 = ar * 64 + (((g0 + 1) ^ (ar & 7)) * 8);

    // ---- B staging (GLOAD, source-swizzled): wave w stages local rows w*32..+32
    const int srow = lane >> 3;
    const int sco = (((lane & 7) ^ srow) << 3);
    const unsigned short* gBw = WmB + ((size_t)(w * 32 + srow)) * MSn + sco;
    char* bD0 = (char*)&Bh[0][0] + w * 4096;
    char* bD1 = (char*)&Bh[1][0] + w * 4096;

    f32x16 acc[4][2];
    #pragma unroll
    for (int uh = 0; uh < 4; ++uh)
        #pragma unroll
        for (int nf = 0; nf < 2; ++nf)
            #pragma unroll
            for (int r = 0; r < 16; ++r) acc[uh][nf][r] = 0.f;

    float4 sA0, sA1, sA2, sA3;

    #define GB(UH, KT, DST) do { \
        const unsigned short* p_ = gBw + (size_t)(UH) * 128 * MSn + (KT) * 64; \
        GLOAD(p_, (DST)); \
        GLOAD(p_ + (size_t)8 * MSn, (DST) + 1024); \
        GLOAD(p_ + (size_t)16 * MSn, (DST) + 2048); \
        GLOAD(p_ + (size_t)24 * MSn, (DST) + 3072); } while (0)

    #define MFMA_PHASE(UH, BUF) do { \
        _Pragma("unroll") \
        for (int ks = 0; ks < 4; ++ks) { \
            bf16x8 bfr0, bfr1; \
            { int ru = wn * 64 + lc; \
              bfr0 = *(const bf16x8*)&(BUF)[ru * 64 + (((ks * 2 + l5) ^ (ru & 7)) * 8)]; } \
            { int ru = wn * 64 + 32 + lc; \
              bfr1 = *(const bf16x8*)&(BUF)[ru * 64 + (((ks * 2 + l5) ^ (ru & 7)) * 8)]; } \
            acc[UH][0] = __builtin_amdgcn_mfma_f32_32x32x16_bf16(afr[ks], bfr0, acc[UH][0], 0, 0, 0); \
            acc[UH][1] = __builtin_amdgcn_mfma_f32_32x32x16_bf16(afr[ks], bfr1, acc[UH][1], 0, 0, 0); \
        } } while (0)

    // ---- prologue: B(0,0) GLOAD; A(0) load+cvt+write; full drain barrier
    GB(0, 0, bD0);
    __builtin_amdgcn_sched_barrier(0);
    sA0 = *(const float4*)(gA);
    sA1 = *(const float4*)(gA + 4);
    sA2 = *(const float4*)(gA + 8);
    sA3 = *(const float4*)(gA + 12);
    *(bf16x8*)&Ah[0][wofA0] = cvt8(sA0, sA1);
    *(bf16x8*)&Ah[0][wofA1] = cvt8(sA2, sA3);
    PIPE_BAR(0);

    #pragma unroll
    for (int kt = 0; kt < 8; ++kt) {
        const int cur = kt & 1;
        const unsigned short* lA = &Ah[cur][0];
        bf16x8 afr[4];

        // P0: GLOAD B(1,kt)->ring1 ; read A frags (held all 4 phases) ; mfma uh0
        GB(1, kt, bD1);
        __builtin_amdgcn_sched_barrier(0);
        #pragma unroll
        for (int ks = 0; ks < 4; ++ks) {
            int r = wm * 32 + lc;
            afr[ks] = *(const bf16x8*)&lA[r * 64 + (((ks * 2 + l5) ^ (r & 7)) * 8)];
        }
        MFMA_PHASE(0, Bh[0]);
        PIPE_BAR(0);

        // P1: GLOAD B(2,kt)->ring0 ; A(kt+1) f32 loads (newer than B2) ; mfma uh1
        GB(2, kt, bD0);
        __builtin_amdgcn_sched_barrier(0);
        if (kt < 7) {
            const float* g = gA + (kt + 1) * 64;
            sA0 = *(const float4*)(g);
            sA1 = *(const float4*)(g + 4);
            sA2 = *(const float4*)(g + 8);
            sA3 = *(const float4*)(g + 12);
        }
        __builtin_amdgcn_sched_barrier(0);
        MFMA_PHASE(1, Bh[1]);
        if (kt < 7) { PIPE_BAR(4); } else { PIPE_BAR(0); }

        // P2: GLOAD B(3,kt)->ring1 ; mfma uh2  (end drains A loads: accepted)
        GB(3, kt, bD1);
        __builtin_amdgcn_sched_barrier(0);
        MFMA_PHASE(2, Bh[0]);
        PIPE_BAR(0);

        // P3: GLOAD B(0,kt+1)->ring0 ; mfma uh3 ; cvt+write A(kt+1) dbuf
        if (kt < 7) { GB(0, kt + 1, bD0); }
        __builtin_amdgcn_sched_barrier(0);
        MFMA_PHASE(3, Bh[1]);
        if (kt < 7) {
            *(bf16x8*)&Ah[cur ^ 1][wofA0] = cvt8(sA0, sA1);
            *(bf16x8*)&Ah[cur ^ 1][wofA1] = cvt8(sA2, sA3);
        }
        PIPE_BAR(0);
    }
    #undef GB
    #undef MFMA_PHASE

    // ---- epilogue: score = sum_u tanh(vals + pq[u]) * Wa[u]
    // C layout: col(u)=lc, local row(t) = wm*32 + (r&3) + 8*(r>>2) + 4*l5
    float pqv[4][2], wav[4][2];
    #pragma unroll
    for (int uh = 0; uh < 4; ++uh)
        #pragma unroll
        for (int nf = 0; nf < 2; ++nf) {
            int u = uh * 128 + wn * 64 + nf * 32 + lc;
            pqv[uh][nf] = pq[(size_t)b * Un + u];
            wav[uh][nf] = Wa[u];
        }
    #pragma unroll
    for (int r = 0; r < 16; ++r) {
        float s = 0.f;
        #pragma unroll
        for (int uh = 0; uh < 4; ++uh)
            #pragma unroll
            for (int nf = 0; nf < 2; ++nf)
                s += tanh_fast(acc[uh][nf][r] + pqv[uh][nf]) * wav[uh][nf];
        s += __shfl_xor(s, 16);
        s += __shfl_xor(s, 8);
        s += __shfl_xor(s, 4);
        s += __shfl_xor(s, 2);
        s += __shfl_xor(s, 1);
        if (lc == 0)
            sc_lds[wn][wm * 32 + (r & 3) + 8 * (r >> 2) + 4 * l5] = s;
    }
    __syncthreads();
    if (tid < TCH) {
        float v = sc_lds[0][tid] + sc_lds[1][tid];
        stot[tid] = v;
        score_out[(size_t)b * Tn + t0 + tid] = v;
    }
    __syncthreads();

    // ---- chunk softmax partials on wave 0
    if (tid < 64) {
        float v = stot[tid];
        float mx = v;
        #pragma unroll
        for (int off = 32; off; off >>= 1) mx = fmaxf(mx, __shfl_xor(mx, off));
        float e = __expf(v - mx);
        wexp[tid] = e;
        float sum = e;
        #pragma unroll
        for (int off = 32; off; off >>= 1) sum += __shfl_xor(sum, off);
        if (tid == 0) {
            pm[b * NCH + chunk] = mx;
            pl[b * NCH + chunk] = sum;
        }
    }
    __syncthreads();

    // ---- ctx partial: thread owns 2 m-cols; keys rows re-read (L2/L3-hot)
    const int c0 = tid * 2;
    const float* kp = keys + ((size_t)b * Tn + t0) * MSn + c0;
    float cx = 0.f, cy = 0.f;
    #pragma unroll 8
    for (int t = 0; t < TCH; ++t) {
        float2 kv = *(const float2*)(kp + (size_t)t * MSn);
        float wt = wexp[t];
        cx += wt * kv.x;
        cy += wt * kv.y;
    }
    float2 cacc = { cx, cy };
    *(float2*)&pctx[((size_t)(b * NCH + chunk)) * MSn + c0] = cacc;
}

// ---------------- merge chunk partials -> total_context ----------------
__global__ __launch_bounds__(512) void merge_kernel(const float* __restrict__ pm,
                                                    const float* __restrict__ pl,
                                                    const float* __restrict__ pctx,
                                                    float* __restrict__ ctx) {
    __shared__ float sm[NCH], sl[NCH];
    const int b = blockIdx.x, tid = threadIdx.x;
    if (tid < NCH) {
        sm[tid] = pm[b * NCH + tid];
        sl[tid] = pl[b * NCH + tid];
    }
    __syncthreads();
    float M = -1e30f;
    #pragma unroll
    for (int c = 0; c < NCH; ++c) M = fmaxf(M, sm[c]);
    float L = 0.f;
    #pragma unroll
    for (int c = 0; c < NCH; ++c) L += sl[c] * __expf(sm[c] - M);
    const float inv = 1.f / L;
    float acc = 0.f;
    #pragma unroll
    for (int c = 0; c < NCH; ++c)
        acc += __expf(sm[c] - M) * pctx[((size_t)(b * NCH + c)) * MSn + tid];
    ctx[(size_t)b * MSn + tid] = acc * inv;
}

extern "C" void kernel_launch(void* const* d_in, const int* in_sizes, int n_in,
                              void* d_out, int out_size, void* d_ws, size_t ws_size,
                              hipStream_t stream) {
    const float* query = (const float*)d_in[0];
    const float* keys  = (const float*)d_in[1];
    const float* Wq    = (const float*)d_in[2];
    const float* Wm    = (const float*)d_in[3];
    const float* Wa    = (const float*)d_in[4];

    float* ctx_out   = (float*)d_out;                    // [64][512]
    float* score_out = (float*)d_out + (size_t)Bn * MSn; // [64][2048]

    char* ws = (char*)d_ws;
    float* ws_pq   = (float*)(ws);                       // 128 KB
    unsigned short* ws_wmbf = (unsigned short*)(ws + 131072);  // 512 KB
    float* ws_pm   = (float*)(ws + 655360);              // 8 KB
    float* ws_pl   = (float*)(ws + 663552);              // 8 KB
    float* ws_pctx = (float*)(ws + 671744);              // 4 MB [64][32][512]

    cvt_kernel<<<(Un * MSn / 4) / 256, 256, 0, stream>>>(Wm, ws_wmbf);
    pq_kernel<<<dim3(Bn, 4), 128, 0, stream>>>(query, Wq, ws_pq);
    fused_kernel<<<dim3(NCH, Bn), 256, 0, stream>>>(keys, ws_wmbf, ws_pq, Wa,
                                                    score_out, ws_pm, ws_pl, ws_pctx);
    merge_kernel<<<Bn, 512, 0, stream>>>(ws_pm, ws_pl, ws_pctx, ctx_out);
}